// Round 1
// baseline (97454.071 us; speedup 1.0000x reference)
//
#include <hip/hip_runtime.h>
#include <math.h>

// Tobit Kalman filter with LSTM dynamics, T=512 sequential steps.
// Persistent-grid design: 256 blocks x 256 threads, custom 2-level global barrier.
// Per step phases (8 grid syncs):
//  A: deferred P-writeback of step t-1  +  LSTM_m gates (Wih part; Whh part precomputed)
//  B: y_raw = hy @ Wfc_m^T + b
//  C: LSTM_f / LSTM_q gates (Wih part)  +  z = H@y_raw + tobit scalar stats
//  D: Fv, Qv  (fc heads of f/q LSTMs)
//  E: M = Pp @ H^T   (Pp = F P F^T + Q folded on the fly)
//  F: R2 = diag(p) H M diag(p)... (= p_i p_j (H M)_ij + diag(rm))
//  G: block 0: Gauss-Jordan inverse of R2 (SPD) in LDS, t1 = W d, V = W*diag(p)
//     blocks 1..255: NEXT step's Whh@h partial gates for all 3 LSTMs (12288 x dot-1024)
//  H: Y = V M^T-ish, MP = diag-scaled M, x_new = y_raw + sum_j p_j M[k,j] t1[j], out

#define TT   512
#define NOBS 64
#define NHID 1024
#define NSTA 128
#define NBLK 256
#define NTHR 256

__device__ __forceinline__ float sigm(float v) { return 1.0f / (1.0f + expf(-v)); }

__device__ __forceinline__ float rsum4 (float s){ s+=__shfl_xor(s,2); s+=__shfl_xor(s,1); return s; }
__device__ __forceinline__ float rsum8 (float s){ s+=__shfl_xor(s,4); s+=__shfl_xor(s,2); s+=__shfl_xor(s,1); return s; }
__device__ __forceinline__ float rsum16(float s){ s+=__shfl_xor(s,8); s+=__shfl_xor(s,4); s+=__shfl_xor(s,2); s+=__shfl_xor(s,1); return s; }
__device__ __forceinline__ float rsum64(float s){
  s+=__shfl_xor(s,32); s+=__shfl_xor(s,16); s+=__shfl_xor(s,8);
  s+=__shfl_xor(s,4);  s+=__shfl_xor(s,2);  s+=__shfl_xor(s,1); return s;
}

// Two-level grid barrier: 8 leaf counters (one per blockIdx&7, XCD-aligned under
// round-robin dispatch) -> root counter -> generation flag. Counters zeroed by
// hipMemsetAsync before launch. All blocks guaranteed co-resident (1 block/CU,
// 33KB LDS -> >=4 blocks/CU capacity).
__device__ __forceinline__ void gsync(unsigned* bar) {
  __syncthreads();
  if (threadIdx.x == 0) {
    __builtin_amdgcn_fence(__ATOMIC_RELEASE, "agent");
    unsigned* leaf = bar + (blockIdx.x & 7) * 32;   // 128B-spaced lines
    unsigned* root = bar + 512;
    unsigned* gen  = bar + 544;
    unsigned g = __hip_atomic_load(gen, __ATOMIC_RELAXED, __HIP_MEMORY_SCOPE_AGENT);
    unsigned a = __hip_atomic_fetch_add(leaf, 1u, __ATOMIC_ACQ_REL, __HIP_MEMORY_SCOPE_AGENT);
    if (a == (unsigned)(NBLK/8 - 1)) {
      __hip_atomic_store(leaf, 0u, __ATOMIC_RELAXED, __HIP_MEMORY_SCOPE_AGENT);
      unsigned r = __hip_atomic_fetch_add(root, 1u, __ATOMIC_ACQ_REL, __HIP_MEMORY_SCOPE_AGENT);
      if (r == 7u) {
        __hip_atomic_store(root, 0u, __ATOMIC_RELAXED, __HIP_MEMORY_SCOPE_AGENT);
        __hip_atomic_store(gen, g + 1u, __ATOMIC_RELEASE, __HIP_MEMORY_SCOPE_AGENT);
      } else {
        while (__hip_atomic_load(gen, __ATOMIC_RELAXED, __HIP_MEMORY_SCOPE_AGENT) == g)
          __builtin_amdgcn_s_sleep(2);
      }
    } else {
      while (__hip_atomic_load(gen, __ATOMIC_RELAXED, __HIP_MEMORY_SCOPE_AGENT) == g)
        __builtin_amdgcn_s_sleep(2);
    }
    __builtin_amdgcn_fence(__ATOMIC_ACQUIRE, "agent");
  }
  __syncthreads();
}

__global__ void __launch_bounds__(NTHR)
tobit_main(const float* __restrict__ x,   const float* __restrict__ y0,
           const float* __restrict__ P0,  const float* __restrict__ H,
           const float* __restrict__ R,   const float* __restrict__ Tl,
           const float* __restrict__ Tu,
           const float* __restrict__ Wih_m, const float* __restrict__ Whh_m,
           const float* __restrict__ bih_m, const float* __restrict__ bhh_m,
           const float* __restrict__ Wfc_m, const float* __restrict__ bfc_m,
           const float* __restrict__ Wih_f, const float* __restrict__ Whh_f,
           const float* __restrict__ bih_f, const float* __restrict__ bhh_f,
           const float* __restrict__ Wfc_f, const float* __restrict__ bfc_f,
           const float* __restrict__ Wih_q, const float* __restrict__ Whh_q,
           const float* __restrict__ bih_q, const float* __restrict__ bhh_q,
           const float* __restrict__ Wfc_q, const float* __restrict__ bfc_q,
           float* __restrict__ out, float* __restrict__ ws)
{
  const int b   = blockIdx.x;
  const int tid = threadIdx.x;
  unsigned* bar = (unsigned*)ws;
  float* base = ws + 1024;            // skip 4KB barrier region

  float* y    = base;                 // 128  filtered state
  float* yraw = base + 128;           // 128  predicted state (pre-tobit)
  float* Fv   = base + 256;           // 128
  float* Qv   = base + 384;           // 128
  float* p64  = base + 512;           // 64
  float* rm64 = base + 576;           // 64
  float* d64  = base + 640;           // 64   innovation yobs - Ey
  float* t1v  = base + 704;           // 64   W @ d
  float* Pm   = base + 768;           // 16384  covariance (post-update of prev step)
  float* Mm   = Pm   + 16384;         // 8192   M = Pp @ H^T
  float* MPm  = Mm   + 8192;          // 8192   MP[k,j] = p_j M[k,j]
  float* R2m  = MPm  + 8192;          // 4096
  float* Vm   = R2m  + 4096;          // 4096   V = W * diag(p)
  float* Ym   = Vm   + 4096;          // 8192   Y[i,m] = sum_j V[i,j] M[m,j]
  float* hb   = Ym   + 8192;          // 6*1024: hy,cy,hF,cF,hQ,cQ
  float* gpart= hb   + 6144;          // 3*4096 precomputed Whh@h + biases

  float* hy = hb;            float* cy = hb + 1024;
  float* hF = hb + 2048;     float* cF = hb + 3072;
  float* hQ = hb + 4096;     float* cQ = hb + 5120;

  __shared__ float lds[8320];         // GJ aug[64][129] + dinv[64]; reused small elsewhere

  // ---- INIT: copy y0/P0, zero h/c, gpart = biases (h=0) ----
  {
    int gid = b * NTHR + tid;         // 0..65535
    if (gid < NSTA) y[gid] = y0[gid];
    if (gid < NSTA*NSTA) Pm[gid] = P0[gid];
    if (gid < 6*NHID) hb[gid] = 0.f;
    if (gid < 4096) {
      gpart[gid]        = bih_m[gid] + bhh_m[gid];
      gpart[4096 + gid] = bih_f[gid] + bhh_f[gid];
      gpart[8192 + gid] = bih_q[gid] + bhh_q[gid];
    }
  }
  gsync(bar);

  for (int t = 0; t < TT; ++t) {
    // ---- Phase A: deferred P-writeback (step t-1) + LSTM_m gates ----
    if (t > 0) {
      int o  = b * 64 + (tid >> 2);       // 0..16383
      int ln = tid & 3;
      int k = o >> 7, m = o & 127;
      float s = 0.f;
      for (int j = ln; j < NOBS; j += 4) s += MPm[k*64 + j] * Ym[j*128 + m];
      s = rsum4(s);
      if (ln == 0) {
        float pv = Fv[k]*Fv[m]*Pm[k*128 + m] - s;
        if (k == m) pv += Qv[k];
        Pm[k*128 + m] = pv;
      }
    }
    {
      int rl = tid >> 4, ln = tid & 15;   // 16 rows x 16 lanes
      int gate = rl >> 2, ul = rl & 3;
      int u = b*4 + ul;
      int r = gate*NHID + u;
      const float* wih = Wih_m + (size_t)r * NSTA;
      float s = 0.f;
      for (int k = ln; k < NSTA; k += 16) s += y[k] * wih[k];
      s = rsum16(s);
      if (ln == 0) lds[rl] = s + gpart[r];
      __syncthreads();
      if (tid < 4) {
        int u2 = b*4 + tid;
        float gi = sigm (lds[     tid]);
        float gf = sigm (lds[ 4 + tid]);
        float gg = tanhf(lds[ 8 + tid]);
        float go = sigm (lds[12 + tid]);
        float c  = gf * cy[u2] + gi * gg;
        cy[u2] = c;
        hy[u2] = go * tanhf(c);
      }
    }
    gsync(bar);

    // ---- Phase B: yraw = hy @ Wfc_m^T + bfc_m ----
    if (b < NSTA) {
      const float* w = Wfc_m + (size_t)b * NHID;
      float s = 0.f;
      for (int k = tid; k < NHID; k += NTHR) s += hy[k] * w[k];
      s = rsum64(s);
      if ((tid & 63) == 0) lds[tid >> 6] = s;
      __syncthreads();
      if (tid == 0) yraw[b] = lds[0] + lds[1] + lds[2] + lds[3] + bfc_m[b];
    }
    gsync(bar);

    // ---- Phase C: LSTM_f / LSTM_q gates + tobit scalar stats ----
    {
      int isF = (b < 128);
      int bb  = isF ? b : b - 128;
      const float* Wih = isF ? Wih_f : Wih_q;
      const float* gp  = gpart + (isF ? 4096 : 8192);
      float* hN = isF ? hF : hQ;
      float* cc = isF ? cF : cQ;
      int rl = tid >> 3, ln = tid & 7;    // 32 rows x 8 lanes
      int gate = rl >> 3, ul = rl & 7;
      int u = bb*8 + ul;
      int r = gate*NHID + u;
      const float* wih = Wih + (size_t)r * NSTA;
      float s = 0.f;
      for (int k = ln; k < NSTA; k += 8) s += yraw[k] * wih[k];
      s = rsum8(s);
      if (ln == 0) lds[rl] = s + gp[r];
      __syncthreads();
      if (tid < 8) {
        int u2 = bb*8 + tid;
        float gi = sigm (lds[     tid]);
        float gf = sigm (lds[ 8 + tid]);
        float gg = tanhf(lds[16 + tid]);
        float go = sigm (lds[24 + tid]);
        float c  = gf * cc[u2] + gi * gg;
        cc[u2] = c;
        hN[u2] = go * tanhf(c);
      }
    }
    if (b < NOBS && tid < 64) {
      float s = H[b*128 + tid] * yraw[tid] + H[b*128 + 64 + tid] * yraw[64 + tid];
      s = rsum64(s);
      if (tid == 0) {
        float z   = s;
        float Rii = R[b*64 + b];
        float r_  = sqrtf(Rii) + 1e-4f;
        float zl  = (Tl[b] - z) / r_;
        float zu  = (Tu[b] - z) / r_;
        const float ISQ2 = 0.70710678118654752f;
        const float IPDF = 0.3989422804014327f;
        float cpl = 0.5f * (1.f + erff(zl * ISQ2));
        float cpu = 0.5f * (1.f + erff(zu * ISQ2));
        float ppl = IPDF * expf(-0.5f * zl * zl);
        float ppu = IPDF * expf(-0.5f * zu * zu);
        float p   = cpu - cpl + 1e-4f;
        float l   = (ppu - ppl) / p;
        float c   = zl*ppl - zu*ppu;
        float Ey  = p * (z - r_*l) + cpl*Tl[b] + (1.f - cpu)*Tu[b];
        p64[b]  = p;
        rm64[b] = Rii * (c/p + 1.f - l*l);
        d64[b]  = x[(size_t)t*NOBS + b] - Ey;
      }
    }
    gsync(bar);

    // ---- Phase D: Fv / Qv ----
    {
      const float* w; const float* bv; float* dst; const float* h; int j;
      if (b < 128) { j = b;       w = Wfc_f + (size_t)j*NHID; bv = bfc_f; dst = Fv; h = hF; }
      else         { j = b - 128; w = Wfc_q + (size_t)j*NHID; bv = bfc_q; dst = Qv; h = hQ; }
      float s = 0.f;
      for (int k = tid; k < NHID; k += NTHR) s += h[k] * w[k];
      s = rsum64(s);
      if ((tid & 63) == 0) lds[tid >> 6] = s;
      __syncthreads();
      if (tid == 0) dst[j] = lds[0] + lds[1] + lds[2] + lds[3] + bv[j];
    }
    gsync(bar);

    // ---- Phase E: M[k,j] = (F P F^T + Q)[k,:] . H[j,:] ----
    {
      int o = b*32 + (tid >> 3), ln = tid & 7;  // 8192 outputs
      int k = o >> 6, j = o & 63;
      const float* prow = Pm + (size_t)k * 128;
      const float* hrow = H  + (size_t)j * 128;
      float s = 0.f;
      for (int m = ln; m < 128; m += 8) s += Fv[m] * prow[m] * hrow[m];
      s = rsum8(s);
      if (ln == 0) Mm[k*64 + j] = Fv[k]*s + Qv[k]*hrow[k];
    }
    gsync(bar);

    // ---- Phase F: R2[i,j] = p_i p_j (H M)[i,j] + diag(rm) ----
    {
      int o = b*16 + (tid >> 4), ln = tid & 15;  // 4096 outputs
      int i = o >> 6, j = o & 63;
      float s = 0.f;
      for (int k = ln; k < 128; k += 16) s += H[i*128 + k] * Mm[k*64 + j];
      s = rsum16(s);
      if (ln == 0) R2m[i*64 + j] = p64[i]*p64[j]*s + ((i == j) ? rm64[i] : 0.f);
    }
    gsync(bar);

    // ---- Phase G: block 0 GJ-inverts R2; others precompute next-step Whh partials ----
    if (b == 0) {
      float* dinv = lds + 64*129;
      for (int e = tid; e < 4096; e += NTHR) {
        int i = e >> 6, j = e & 63;
        lds[i*129 + j]      = R2m[e];
        lds[i*129 + 64 + j] = (i == j) ? 1.f : 0.f;
      }
      __syncthreads();
      for (int kp = 0; kp < 64; ++kp) {
        float piv = 1.0f / lds[kp*129 + kp];
        if (tid == 0) dinv[kp] = piv;
        int i = tid >> 2, cq = tid & 3;
        if (i != kp) {
          float f = lds[i*129 + kp] * piv;
          for (int c = kp + 1 + cq; c < 64; c += 4)  lds[i*129 + c] -= f * lds[kp*129 + c];
          for (int c = 64 + cq;     c < 128; c += 4) lds[i*129 + c] -= f * lds[kp*129 + c];
        }
        __syncthreads();
      }
      for (int e = tid; e < 4096; e += NTHR) {
        int i = e >> 6, j = e & 63;
        Vm[e] = lds[i*129 + 64 + j] * dinv[i] * p64[j];
      }
      if (tid < 64) {
        float s = 0.f;
        for (int j = 0; j < 64; ++j) s += lds[tid*129 + 64 + j] * d64[j];
        t1v[tid] = s * dinv[tid];
      }
    } else {
      // 12288 rows (3 LSTMs x 4096) of dot-1024, teams of 16 lanes
      int team = (b - 1)*16 + (tid >> 4), ln = tid & 15;
      for (int rho = team; rho < 12288; rho += 255*16) {
        int mat = rho >> 12, r = rho & 4095;
        const float* whh; const float* hsrc; const float* bi; const float* bh;
        if      (mat == 0) { whh = Whh_m; hsrc = hy; bi = bih_m; bh = bhh_m; }
        else if (mat == 1) { whh = Whh_f; hsrc = hF; bi = bih_f; bh = bhh_f; }
        else               { whh = Whh_q; hsrc = hQ; bi = bih_q; bh = bhh_q; }
        const float* wr = whh + (size_t)r * NHID;
        float s = 0.f;
        for (int k = ln; k < NHID; k += 16) s += hsrc[k] * wr[k];
        s = rsum16(s);
        if (ln == 0) gpart[mat*4096 + r] = s + bi[r] + bh[r];
      }
    }
    gsync(bar);

    // ---- Phase H: Y = V M^T(row-dots), MP, x_new, out ----
    {
      int o = b*32 + (tid >> 3), ln = tid & 7;   // 8192 outputs
      int i = o >> 7, m = o & 127;
      float s = 0.f;
      for (int j = ln; j < NOBS; j += 8) s += Vm[i*64 + j] * Mm[m*64 + j];
      s = rsum8(s);
      if (ln == 0) Ym[i*128 + m] = s;
      if (tid < 32) {
        int e = b*32 + tid;
        int jj = e & 63;
        MPm[e] = p64[jj] * Mm[e];
      }
    }
    if (b == 0 && tid < NSTA) {
      float s = yraw[tid];
      const float* mrow = Mm + tid*64;
      for (int j = 0; j < NOBS; ++j) s += p64[j] * mrow[j] * t1v[j];
      y[tid] = s;
      out[(size_t)t*NSTA + tid] = s;
    }
    gsync(bar);
  }
}

extern "C" void kernel_launch(void* const* d_in, const int* in_sizes, int n_in,
                              void* d_out, int out_size, void* d_ws, size_t ws_size,
                              hipStream_t stream) {
  const float* x     = (const float*)d_in[0];
  const float* y0    = (const float*)d_in[1];
  const float* P0    = (const float*)d_in[2];
  const float* H     = (const float*)d_in[3];
  const float* R     = (const float*)d_in[4];
  const float* Tl    = (const float*)d_in[5];
  const float* Tu    = (const float*)d_in[6];
  const float* Wih_m = (const float*)d_in[7];
  const float* Whh_m = (const float*)d_in[8];
  const float* bih_m = (const float*)d_in[9];
  const float* bhh_m = (const float*)d_in[10];
  const float* Wfc_m = (const float*)d_in[11];
  const float* bfc_m = (const float*)d_in[12];
  const float* Wih_f = (const float*)d_in[13];
  const float* Whh_f = (const float*)d_in[14];
  const float* bih_f = (const float*)d_in[15];
  const float* bhh_f = (const float*)d_in[16];
  const float* Wfc_f = (const float*)d_in[17];
  const float* bfc_f = (const float*)d_in[18];
  const float* Wih_q = (const float*)d_in[19];
  const float* Whh_q = (const float*)d_in[20];
  const float* bih_q = (const float*)d_in[21];
  const float* bhh_q = (const float*)d_in[22];
  const float* Wfc_q = (const float*)d_in[23];
  const float* bfc_q = (const float*)d_in[24];
  float* out = (float*)d_out;
  float* ws  = (float*)d_ws;

  // zero the barrier counters (first 4KB of ws) — ws is re-poisoned before every call
  hipMemsetAsync(d_ws, 0, 4096, stream);

  hipLaunchKernelGGL(tobit_main, dim3(NBLK), dim3(NTHR), 0, stream,
                     x, y0, P0, H, R, Tl, Tu,
                     Wih_m, Whh_m, bih_m, bhh_m, Wfc_m, bfc_m,
                     Wih_f, Whh_f, bih_f, bhh_f, Wfc_f, bfc_f,
                     Wih_q, Whh_q, bih_q, bhh_q, Wfc_q, bfc_q,
                     out, ws);
}

// Round 2
// 96504.291 us; speedup vs baseline: 1.0098x; 1.0098x over previous
//
#include <hip/hip_runtime.h>
#include <math.h>

// Tobit Kalman filter with LSTM dynamics, T=512 sequential steps.
// Persistent-grid: 256 blocks x 256 threads (1/CU), custom 2-level barrier.
// ALL LSTM weights (Whh 48MB, Wih 6MB, biases) live in REGISTERS: each block
// owns 48 gate rows (16 of LSTM_m for its 4 units; 32 of LSTM_f or LSTM_q for
// its 8 units); each 16-lane team owns 3 rows (1 m + 2 f/q), 16+2 float4 per
// row per lane. h-vectors are broadcast through LDS for the Whh dots.
// Phases per step (7 grid syncs):
//  A: y(t-1) finalize + out + Ym/MP shadow (P-update part 1) + LSTM_m gates
//  B: yraw = hy@Wfc_m^T [blk 0-127] | P writeback (part 2)  [blk 128-255]
//  C: LSTM_f/q gates (Wih part + reg-held Whh part) + tobit scalar stats
//  D: Fv/Qv fc heads; block 0 also: its 48 Whh-row dots (hy,hF via LDS)
//  E: M = (F P F^T + Q) @ H^T
//  F: R2 = diag(p) (H M) diag(p) + diag(rm)
//  G: block 0: Gauss-Jordan inverse of R2 in LDS -> Vm, t1
//     blocks 1-255: their 48 Whh-row dots for NEXT step (results stay in regs)

#define TT   512
#define NOBS 64
#define NHID 1024
#define NSTA 128
#define NBLK 256
#define NTHR 256

__device__ __forceinline__ float sigm(float v) { return 1.0f / (1.0f + expf(-v)); }

__device__ __forceinline__ float rsum8 (float s){ s+=__shfl_xor(s,4); s+=__shfl_xor(s,2); s+=__shfl_xor(s,1); return s; }
__device__ __forceinline__ float rsum16(float s){ s+=__shfl_xor(s,8); s+=__shfl_xor(s,4); s+=__shfl_xor(s,2); s+=__shfl_xor(s,1); return s; }
__device__ __forceinline__ float rsum64(float s){
  s+=__shfl_xor(s,32); s+=__shfl_xor(s,16); s+=__shfl_xor(s,8);
  s+=__shfl_xor(s,4);  s+=__shfl_xor(s,2);  s+=__shfl_xor(s,1); return s;
}

// Two-level grid barrier, hierarchical arrival AND release.
// bar[(b&7)*64]: leaf arrival counters (256B apart). bar[512]: root counter.
// bar[576]: root generation. bar[640+(b&7)*64]: leaf release flags.
__device__ __forceinline__ void gsync(unsigned* bar) {
  __syncthreads();
  if (threadIdx.x == 0) {
    __builtin_amdgcn_fence(__ATOMIC_RELEASE, "agent");
    unsigned* leafc = bar + (blockIdx.x & 7) * 64;
    unsigned* rootc = bar + 512;
    unsigned* rootg = bar + 576;
    unsigned* leaff = bar + 640 + (blockIdx.x & 7) * 64;
    unsigned g = __hip_atomic_load(rootg, __ATOMIC_RELAXED, __HIP_MEMORY_SCOPE_AGENT);
    unsigned a = __hip_atomic_fetch_add(leafc, 1u, __ATOMIC_ACQ_REL, __HIP_MEMORY_SCOPE_AGENT);
    if (a == 31u) {
      __hip_atomic_store(leafc, 0u, __ATOMIC_RELAXED, __HIP_MEMORY_SCOPE_AGENT);
      unsigned r = __hip_atomic_fetch_add(rootc, 1u, __ATOMIC_ACQ_REL, __HIP_MEMORY_SCOPE_AGENT);
      if (r == 7u) {
        __hip_atomic_store(rootc, 0u, __ATOMIC_RELAXED, __HIP_MEMORY_SCOPE_AGENT);
        __hip_atomic_store(rootg, g + 1u, __ATOMIC_RELEASE, __HIP_MEMORY_SCOPE_AGENT);
      } else {
        while (__hip_atomic_load(rootg, __ATOMIC_RELAXED, __HIP_MEMORY_SCOPE_AGENT) == g)
          __builtin_amdgcn_s_sleep(1);
      }
      __hip_atomic_store(leaff, g + 1u, __ATOMIC_RELEASE, __HIP_MEMORY_SCOPE_AGENT);
    } else {
      while (__hip_atomic_load(leaff, __ATOMIC_RELAXED, __HIP_MEMORY_SCOPE_AGENT) == g)
        __builtin_amdgcn_s_sleep(1);
    }
    __builtin_amdgcn_fence(__ATOMIC_ACQUIRE, "agent");
  }
  __syncthreads();
}

// reg-array dot helpers: static indices only (keep arrays in VGPRs)
#define DOT16(RES, W, BASE) do { float s_ = 0.f; \
  _Pragma("unroll") for (int c_ = 0; c_ < 16; ++c_) { float4 h_ = hlds4[(BASE) + c_*16 + ln]; \
    s_ += W[c_].x*h_.x + W[c_].y*h_.y + W[c_].z*h_.z + W[c_].w*h_.w; } RES = s_; } while (0)
#define DOT2(RES, W) do { float s_ = 0.f; \
  _Pragma("unroll") for (int c_ = 0; c_ < 2; ++c_) { float4 h_ = ylds4[c_*16 + ln]; \
    s_ += W[c_].x*h_.x + W[c_].y*h_.y + W[c_].z*h_.z + W[c_].w*h_.w; } RES = s_; } while (0)

__global__ void __launch_bounds__(NTHR, 1)
tobit_main(const float* __restrict__ x,   const float* __restrict__ y0,
           const float* __restrict__ P0,  const float* __restrict__ H,
           const float* __restrict__ R,   const float* __restrict__ Tl,
           const float* __restrict__ Tu,
           const float* __restrict__ Wih_m, const float* __restrict__ Whh_m,
           const float* __restrict__ bih_m, const float* __restrict__ bhh_m,
           const float* __restrict__ Wfc_m, const float* __restrict__ bfc_m,
           const float* __restrict__ Wih_f, const float* __restrict__ Whh_f,
           const float* __restrict__ bih_f, const float* __restrict__ bhh_f,
           const float* __restrict__ Wfc_f, const float* __restrict__ bfc_f,
           const float* __restrict__ Wih_q, const float* __restrict__ Whh_q,
           const float* __restrict__ bih_q, const float* __restrict__ bhh_q,
           const float* __restrict__ Wfc_q, const float* __restrict__ bfc_q,
           float* __restrict__ out, float* __restrict__ ws)
{
  const int b   = blockIdx.x;
  const int tid = threadIdx.x;
  const int w   = tid >> 4;     // team 0..15
  const int ln  = tid & 15;     // lane in team
  unsigned* bar = (unsigned*)ws;

  float* yraw_g = ws + 2048;    // 128
  float* Fv_g   = ws + 2176;    // 128
  float* Qv_g   = ws + 2304;    // 128
  float* p64_g  = ws + 2432;    // 64
  float* rm64_g = ws + 2496;    // 64
  float* d64_g  = ws + 2560;    // 64
  float* t1v_g  = ws + 2624;    // 64
  float* hy_g   = ws + 2688;    // 1024
  float* hF_g   = ws + 3712;    // 1024
  float* hQ_g   = ws + 4736;    // 1024
  float* Pm_g   = ws + 5760;    // 16384
  float* Mm_g   = ws + 22144;   // 8192
  float* MPm_g  = ws + 30336;   // 8192
  float* Ym_g   = ws + 38528;   // 8192
  float* Vm_g   = ws + 46720;   // 4096
  float* R2m_g  = ws + 50816;   // 4096

  __shared__ __align__(16) float slds[8320];   // GJ aug[64][129]+dinv[64]; reused scratch
  __shared__ float4 hlds4[512];                // h broadcast: [0..255]=hy, [256..511]=hF|hQ
  float4* ylds4 = (float4*)(slds + 64);        // y / yraw copy, floats 64..191

  // ---- ownership & persistent register weights ----
  const int  bb  = b & 127;
  const bool isF = (b < 128);
  const float* WhhX = isF ? Whh_f : Whh_q;
  const float* WihX = isF ? Wih_f : Wih_q;
  const float* bihX = isF ? bih_f : bih_q;
  const float* bhhX = isF ? bhh_f : bhh_q;
  float* hfq_g = isF ? hF_g : hQ_g;

  const int r_m  = (w >> 2) * NHID + b * 4 + (w & 3);          // m-row (gate*1024+unit)
  const int idx0 = w * 2, idx1 = w * 2 + 1;                    // fq row idx in block 0..31
  const int r_f0 = (idx0 >> 3) * NHID + bb * 8 + (idx0 & 7);
  const int r_f1 = (idx1 >> 3) * NHID + bb * 8 + (idx1 & 7);

  float4 wm[16], wf0[16], wf1[16], im[2], if0v[2], if1v[2];
  #pragma unroll
  for (int c = 0; c < 16; ++c) {
    wm[c]  = *(const float4*)(Whh_m + (size_t)r_m  * NHID + (c*16 + ln) * 4);
    wf0[c] = *(const float4*)(WhhX  + (size_t)r_f0 * NHID + (c*16 + ln) * 4);
    wf1[c] = *(const float4*)(WhhX  + (size_t)r_f1 * NHID + (c*16 + ln) * 4);
  }
  #pragma unroll
  for (int c = 0; c < 2; ++c) {
    im[c]   = *(const float4*)(Wih_m + (size_t)r_m  * NSTA + (c*16 + ln) * 4);
    if0v[c] = *(const float4*)(WihX  + (size_t)r_f0 * NSTA + (c*16 + ln) * 4);
    if1v[c] = *(const float4*)(WihX  + (size_t)r_f1 * NSTA + (c*16 + ln) * 4);
  }
  const float bm_b  = bih_m[r_m]  + bhh_m[r_m];
  const float bf0_b = bihX[r_f0] + bhhX[r_f0];
  const float bf1_b = bihX[r_f1] + bhhX[r_f1];
  float hm_r = 0.f, hf0_r = 0.f, hf1_r = 0.f;   // Whh@h partials (allreduced per team)
  float cm = 0.f, cf = 0.f;                      // cell states (tid<4 / tid<8 own them)

  // ---- init: P <- P0 ----
  {
    int gid = b * NTHR + tid;
    if (gid < NSTA * NSTA) Pm_g[gid] = P0[gid];
  }
  gsync(bar);

  for (int t = 0; t < TT; ++t) {
    // ================= Phase A =================
    if (t > 0) {
      { // finalize y(t-1) = yraw + K d   (2 lanes per element)
        int sidx = tid >> 1, half = tid & 1;
        const float* mrow = Mm_g + sidx * 64 + half * 32;
        const float* pp = p64_g + half * 32;
        const float* tt = t1v_g + half * 32;
        float acc = 0.f;
        #pragma unroll
        for (int j = 0; j < 32; ++j) acc += pp[j] * mrow[j] * tt[j];
        acc += __shfl_xor(acc, 1);
        if (half == 0) {
          float yv = yraw_g[sidx] + acc;
          slds[64 + sidx] = yv;
          if (b == 0) out[(size_t)(t - 1) * NSTA + sidx] = yv;
        }
      }
      { // shadow: Ym[i][m] = sum_j Vm[i][j] Mm[m][j]
        int o = b * 32 + (tid >> 3), ln8 = tid & 7;
        int i = o >> 7, m = o & 127;
        float s = 0.f;
        for (int j = ln8; j < NOBS; j += 8) s += Vm_g[i*64 + j] * Mm_g[m*64 + j];
        s = rsum8(s);
        if (ln8 == 0) Ym_g[i*128 + m] = s;
      }
      if (tid < 32) { int e = b * 32 + tid; MPm_g[e] = p64_g[e & 63] * Mm_g[e]; }
    } else {
      if (tid < NSTA) slds[64 + tid] = y0[tid];
    }
    __syncthreads();
    { // LSTM_m gates: Wih@y (regs) + reg-held Whh part + bias
      float s; DOT2(s, im);
      s = rsum16(s) + hm_r + bm_b;
      if (ln == 0) slds[w] = s;
    }
    __syncthreads();
    if (tid < 4) {
      float gi = sigm(slds[tid]),     gf = sigm(slds[4 + tid]);
      float gg = tanhf(slds[8 + tid]), go = sigm(slds[12 + tid]);
      cm = gf * cm + gi * gg;
      hy_g[b * 4 + tid] = go * tanhf(cm);
    }
    gsync(bar);

    // ================= Phase B =================
    if (b < NSTA) { // yraw[b] = hy . Wfc_m[b] + bfc_m[b]
      float4 wv = ((const float4*)(Wfc_m + (size_t)b * NHID))[tid];
      float4 hv = ((const float4*)hy_g)[tid];
      float s = wv.x*hv.x + wv.y*hv.y + wv.z*hv.z + wv.w*hv.w;
      s = rsum64(s);
      if ((tid & 63) == 0) slds[tid >> 6] = s;
      __syncthreads();
      if (tid == 0) yraw_g[b] = slds[0] + slds[1] + slds[2] + slds[3] + bfc_m[b];
    } else if (t > 0) { // P writeback (row k), part 2 of deferred update
      int k = b - NSTA;
      int m = tid >> 1, half = tid & 1;
      const float* mp = MPm_g + k * 64 + half * 32;
      float s = 0.f;
      #pragma unroll
      for (int j = 0; j < 32; ++j) s += mp[j] * Ym_g[(half * 32 + j) * 128 + m];
      s += __shfl_xor(s, 1);
      if (half == 0) {
        float pv = Fv_g[k] * Fv_g[m] * Pm_g[k*128 + m] - s;
        if (k == m) pv += Qv_g[k];
        Pm_g[k*128 + m] = pv;
      }
    }
    gsync(bar);

    // ================= Phase C =================
    if (tid < NSTA) slds[64 + tid] = yraw_g[tid];
    __syncthreads();
    { // LSTM_f / LSTM_q gates
      float s0, s1; DOT2(s0, if0v); DOT2(s1, if1v);
      s0 = rsum16(s0) + hf0_r + bf0_b;
      s1 = rsum16(s1) + hf1_r + bf1_b;
      if (ln == 0) { slds[idx0] = s0; slds[idx1] = s1; }
    }
    __syncthreads();
    if (tid < 8) {
      float gi = sigm(slds[tid]),      gf = sigm(slds[8 + tid]);
      float gg = tanhf(slds[16 + tid]), go = sigm(slds[24 + tid]);
      cf = gf * cf + gi * gg;
      hfq_g[bb * 8 + tid] = go * tanhf(cf);
    }
    if (b < NOBS && tid < 64) { // tobit scalar stats for obs b
      float s = H[b*128 + tid] * slds[64 + tid] + H[b*128 + 64 + tid] * slds[128 + tid];
      s = rsum64(s);
      if (tid == 0) {
        float z   = s;
        float Rii = R[b*64 + b];
        float r_  = sqrtf(Rii) + 1e-4f;
        float zl  = (Tl[b] - z) / r_;
        float zu  = (Tu[b] - z) / r_;
        const float ISQ2 = 0.70710678118654752f;
        const float IPDF = 0.3989422804014327f;
        float cpl = 0.5f * (1.f + erff(zl * ISQ2));
        float cpu = 0.5f * (1.f + erff(zu * ISQ2));
        float ppl = IPDF * expf(-0.5f * zl * zl);
        float ppu = IPDF * expf(-0.5f * zu * zu);
        float p   = cpu - cpl + 1e-4f;
        float l   = (ppu - ppl) / p;
        float c   = zl*ppl - zu*ppu;
        float Ey  = p * (z - r_*l) + cpl*Tl[b] + (1.f - cpu)*Tu[b];
        p64_g[b]  = p;
        rm64_g[b] = Rii * (c/p + 1.f - l*l);
        d64_g[b]  = x[(size_t)t*NOBS + b] - Ey;
      }
    }
    gsync(bar);

    // ================= Phase D =================
    { // Fv[j] / Qv[j] fc heads (one row per block)
      int j = isF ? b : b - NSTA;
      const float* wrow = (isF ? Wfc_f : Wfc_q) + (size_t)j * NHID;
      const float* hsrc = isF ? hF_g : hQ_g;
      float4 wv = ((const float4*)wrow)[tid];
      float4 hv = ((const float4*)hsrc)[tid];
      float s = wv.x*hv.x + wv.y*hv.y + wv.z*hv.z + wv.w*hv.w;
      s = rsum64(s);
      if ((tid & 63) == 0) slds[tid >> 6] = s;
      __syncthreads();
      if (tid == 0) (isF ? Fv_g : Qv_g)[j] = slds[0]+slds[1]+slds[2]+slds[3] + (isF ? bfc_f : bfc_q)[j];
    }
    if (b == 0) { // block 0 does its Whh dots here (it runs GJ during phase G)
      hlds4[tid]       = ((const float4*)hy_g)[tid];
      hlds4[256 + tid] = ((const float4*)hF_g)[tid];
      __syncthreads();
      float s;
      DOT16(s, wm, 0);    hm_r  = rsum16(s);
      DOT16(s, wf0, 256); hf0_r = rsum16(s);
      DOT16(s, wf1, 256); hf1_r = rsum16(s);
    }
    gsync(bar);

    // ================= Phase E: M = (F P F^T + Q) H^T =================
    {
      int o = b * 32 + (tid >> 3), ln8 = tid & 7;
      int k = o >> 6, j = o & 63;
      const float* prow = Pm_g + (size_t)k * 128;
      const float* hrow = H   + (size_t)j * 128;
      float s = 0.f;
      for (int m = ln8; m < 128; m += 8) s += Fv_g[m] * prow[m] * hrow[m];
      s = rsum8(s);
      if (ln8 == 0) Mm_g[k*64 + j] = Fv_g[k]*s + Qv_g[k]*hrow[k];
    }
    gsync(bar);

    // ================= Phase F: R2 = pp^T.(H M) + diag(rm) =================
    {
      int o = b * 16 + (tid >> 4), i = o >> 6, j = o & 63;
      float s = 0.f;
      for (int k = ln; k < 128; k += 16) s += H[i*128 + k] * Mm_g[k*64 + j];
      s = rsum16(s);
      if (ln == 0) R2m_g[i*64 + j] = p64_g[i]*p64_g[j]*s + ((i == j) ? rm64_g[i] : 0.f);
    }
    gsync(bar);

    // ================= Phase G =================
    if (b == 0) { // Gauss-Jordan inverse of R2 (SPD, no pivoting) in LDS
      for (int e = tid; e < 4096; e += NTHR) {
        int i = e >> 6, j = e & 63;
        slds[i*129 + j]      = R2m_g[e];
        slds[i*129 + 64 + j] = (i == j) ? 1.f : 0.f;
      }
      __syncthreads();
      float* dinv = slds + 8256;
      for (int kp = 0; kp < 64; ++kp) {
        float piv = 1.0f / slds[kp*129 + kp];
        if (tid == 0) dinv[kp] = piv;
        int i = tid >> 2, cq = tid & 3;
        if (i != kp) {
          float f = slds[i*129 + kp] * piv;
          for (int c = kp + 1 + cq; c < 64; c += 4)  slds[i*129 + c] -= f * slds[kp*129 + c];
          for (int c = 64 + cq;     c < 128; c += 4) slds[i*129 + c] -= f * slds[kp*129 + c];
        }
        __syncthreads();
      }
      for (int e = tid; e < 4096; e += NTHR) {
        int i = e >> 6, j = e & 63;
        Vm_g[e] = slds[i*129 + 64 + j] * dinv[i] * p64_g[j];
      }
      if (tid < 64) {
        float s = 0.f;
        for (int j = 0; j < 64; ++j) s += slds[tid*129 + 64 + j] * d64_g[j];
        t1v_g[tid] = s * dinv[tid];
      }
    } else { // Whh @ h for next step, results stay in registers
      hlds4[tid]       = ((const float4*)hy_g)[tid];
      hlds4[256 + tid] = ((const float4*)hfq_g)[tid];
      __syncthreads();
      float s;
      DOT16(s, wm, 0);    hm_r  = rsum16(s);
      DOT16(s, wf0, 256); hf0_r = rsum16(s);
      DOT16(s, wf1, 256); hf1_r = rsum16(s);
    }
    gsync(bar);
  }

  // epilogue: out[T-1]
  if (b == 0 && tid < NSTA) {
    float s = yraw_g[tid];
    const float* mrow = Mm_g + tid * 64;
    for (int j = 0; j < NOBS; ++j) s += p64_g[j] * mrow[j] * t1v_g[j];
    out[(size_t)(TT - 1) * NSTA + tid] = s;
  }
}

extern "C" void kernel_launch(void* const* d_in, const int* in_sizes, int n_in,
                              void* d_out, int out_size, void* d_ws, size_t ws_size,
                              hipStream_t stream) {
  const float* x     = (const float*)d_in[0];
  const float* y0    = (const float*)d_in[1];
  const float* P0    = (const float*)d_in[2];
  const float* H     = (const float*)d_in[3];
  const float* R     = (const float*)d_in[4];
  const float* Tl    = (const float*)d_in[5];
  const float* Tu    = (const float*)d_in[6];
  const float* Wih_m = (const float*)d_in[7];
  const float* Whh_m = (const float*)d_in[8];
  const float* bih_m = (const float*)d_in[9];
  const float* bhh_m = (const float*)d_in[10];
  const float* Wfc_m = (const float*)d_in[11];
  const float* bfc_m = (const float*)d_in[12];
  const float* Wih_f = (const float*)d_in[13];
  const float* Whh_f = (const float*)d_in[14];
  const float* bih_f = (const float*)d_in[15];
  const float* bhh_f = (const float*)d_in[16];
  const float* Wfc_f = (const float*)d_in[17];
  const float* bfc_f = (const float*)d_in[18];
  const float* Wih_q = (const float*)d_in[19];
  const float* Whh_q = (const float*)d_in[20];
  const float* bih_q = (const float*)d_in[21];
  const float* bhh_q = (const float*)d_in[22];
  const float* Wfc_q = (const float*)d_in[23];
  const float* bfc_q = (const float*)d_in[24];
  float* out = (float*)d_out;
  float* ws  = (float*)d_ws;

  // zero the barrier region (first 8KB of ws)
  hipMemsetAsync(d_ws, 0, 8192, stream);

  hipLaunchKernelGGL(tobit_main, dim3(NBLK), dim3(NTHR), 0, stream,
                     x, y0, P0, H, R, Tl, Tu,
                     Wih_m, Whh_m, bih_m, bhh_m, Wfc_m, bfc_m,
                     Wih_f, Whh_f, bih_f, bhh_f, Wfc_f, bfc_f,
                     Wih_q, Whh_q, bih_q, bhh_q, Wfc_q, bfc_q,
                     out, ws);
}